// Round 10
// baseline (117.381 us; speedup 1.0000x reference)
//
#include <hip/hip_runtime.h>

// VectorQuantizer R9: input (16,64,64,64) f32 channel-first, codebook (1024,64) f32.
// out = [quantized (16,64,64,64) f32 | indices (16,64,64) as f32].
//
// Fused single kernel, codebook LDS-resident. Block = 512 thr / 8 waves /
// 256 tokens; wave = 32 tokens x full K. 4 rotated K-quarter phases:
// stage 256 codewords f32 -> f16(-2c) hi/lo fragments (64 KB LDS) + exact
// f32 esq, then 8 tiles of mfma_f32_32x32x16_f16 fed by ds_read_b128.
// Numerics (R6/R7-verified): c hi+lo, x hi+lo, 3 chains (drop lo*lo):
//   accA = esq-fold + sum(ch*xh); accB = sum(ch*xl) + sum(cl*xh);
//   score = accA[r]+accB[r]; sigma ~6e-5. Exact value+slot top-2 tracking;
//   gap < EPS=2e-3 (33 sigma) -> block-cooperative exact fp32 rescan with
//   ascending-k tie-break (exact ties always flagged => reference argmin).

typedef _Float16 v8h  __attribute__((ext_vector_type(8)));
typedef _Float16 v4h  __attribute__((ext_vector_type(4)));
typedef float    v16f __attribute__((ext_vector_type(16)));

constexpr int   D         = 64;
constexpr int   K         = 1024;
constexpr int   HW        = 4096;
constexpr int   DHW       = D * HW;
constexpr int   OUT_ELEMS = 16 * DHW;
constexpr float EPS       = 2e-3f;

__global__ __launch_bounds__(512, 2) void vq_fused(
    const float* __restrict__ input,
    const float* __restrict__ codebook,
    float* __restrict__ out)
{
    // A frags: s_ch[tile][hl][kc][lane][j] -> A[row=t*32+(lane&31)][k=kc*16+(lane>>5)*8+j]
    __shared__ _Float16 s_ch[8][2][4][64][8];   // 64 KB, current K-quarter, -2c hi/lo
    __shared__ _Float16 s_bf[8][2][4][64][8];   // 64 KB, B frags hi/lo per token-group
    __shared__ float    s_esq[K];               // 4 KB exact f32 e_sq
    __shared__ int      s_idx[256];
    __shared__ int      s_list[256];
    __shared__ int      s_cnt;
    __shared__ float    s_xf[64];
    __shared__ float    s_redv[8];
    __shared__ int      s_redk[8];

    const int tid  = threadIdx.x;
    const int lane = tid & 63;
    const int q    = __builtin_amdgcn_readfirstlane(tid >> 6);  // wave = token group
    const int lh   = lane >> 5;
    const int tok0 = blockIdx.x * 256;
    const int b    = tok0 >> 12;
    const int hwb  = tok0 & 4095;

    if (tid == 0) s_cnt = 0;

    // ---- B staging: 256 tokens x 64 ch, coalesced float4, hi/lo split ----
    {
        const float* xb = input + (size_t)b * DHW + hwb;
        #pragma unroll
        for (int pass = 0; pass < 8; ++pass) {
            const int g   = pass * 512 + tid;
            const int d   = g >> 6;                 // 0..63
            const int hw4 = (g & 63) * 4;
            const float4 v = *(const float4*)(xb + (size_t)d * HW + hw4);
            const float vv[4] = {v.x, v.y, v.z, v.w};
            const int kc = d >> 4, lhd = (d >> 3) & 1, j = d & 7;
            #pragma unroll
            for (int u = 0; u < 4; ++u) {
                const int tk  = hw4 + u;
                const int g2  = tk >> 5, col = tk & 31;
                const float f = vv[u];
                const _Float16 fh = (_Float16)f;
                s_bf[g2][0][kc][lhd * 32 + col][j] = fh;
                s_bf[g2][1][kc][lhd * 32 + col][j] = (_Float16)(f - (float)fh);
            }
        }
    }

    v8h b5 = {};                       // ones at k=0,1 (pairs with esq fold)
    if (lh == 0) { b5[0] = (_Float16)1.0f; b5[1] = (_Float16)1.0f; }

    v8h bh[4], bl[4];
    v16f Z = {0,0,0,0,0,0,0,0,0,0,0,0,0,0,0,0};
    const float INF = __builtin_huge_valf();
    float bv = INF, b2 = INF;
    int   sl = 0;
    bool  bloaded = false;

    #pragma unroll 1
    for (int p = 0; p < 4; ++p) {
        const int phR = (blockIdx.x + p) & 3;      // rotated K-quarter
        const int cw0 = phR * 256;

        // ---- stage K-quarter: coalesced f32 read -> hi/lo frags + exact esq ----
        #pragma unroll
        for (int pass = 0; pass < 8; ++pass) {
            const int g   = pass * 512 + tid;
            const int cwl = g >> 4;                // 0..255
            const int dq  = (g & 15) * 4;
            const float4 v = *(const float4*)(codebook + (size_t)(cw0 + cwl) * D + dq);
            float part = fmaf(v.x, v.x, fmaf(v.y, v.y, fmaf(v.z, v.z, v.w * v.w)));
            part += __shfl_xor(part, 1, 64);
            part += __shfl_xor(part, 2, 64);
            part += __shfl_xor(part, 4, 64);
            part += __shfl_xor(part, 8, 64);
            if ((tid & 15) == 0) s_esq[cw0 + cwl] = part;
            const int T  = cwl >> 5, lc = cwl & 31;
            const int kc = dq >> 4, lhd = (dq >> 3) & 1, j0 = dq & 7;
            const float vv[4] = {v.x, v.y, v.z, v.w};
            v4h hh, hl;
            #pragma unroll
            for (int u = 0; u < 4; ++u) {
                const float w = -2.0f * vv[u];
                const _Float16 wh = (_Float16)w;
                hh[u] = wh;
                hl[u] = (_Float16)(w - (float)wh);
            }
            *(v4h*)&s_ch[T][0][kc][lhd * 32 + lc][j0] = hh;
            *(v4h*)&s_ch[T][1][kc][lhd * 32 + lc][j0] = hl;
        }
        __syncthreads();

        if (!bloaded) {
            bloaded = true;
            #pragma unroll
            for (int kc = 0; kc < 4; ++kc) {
                bh[kc] = *(const v8h*)&s_bf[q][0][kc][lane][0];
                bl[kc] = *(const v8h*)&s_bf[q][1][kc][lane][0];
            }
        }

        // ---- compute 8 tiles from LDS: 13 MFMA each ----
        #pragma unroll 1
        for (int t = 0; t < 8; ++t) {
            const int Tg = phR * 8 + t;
            float e = 0.0f;
            if (lane < 32) e = s_esq[cw0 + t * 32 + lane];
            v8h ae = {};
            const _Float16 eh = (_Float16)e;
            ae[0] = eh;
            ae[1] = (_Float16)(e - (float)eh);

            const v8h ah0 = *(const v8h*)&s_ch[t][0][0][lane][0];
            const v8h ah1 = *(const v8h*)&s_ch[t][0][1][lane][0];
            const v8h ah2 = *(const v8h*)&s_ch[t][0][2][lane][0];
            const v8h ah3 = *(const v8h*)&s_ch[t][0][3][lane][0];
            const v8h al0 = *(const v8h*)&s_ch[t][1][0][lane][0];
            const v8h al1 = *(const v8h*)&s_ch[t][1][1][lane][0];
            const v8h al2 = *(const v8h*)&s_ch[t][1][2][lane][0];
            const v8h al3 = *(const v8h*)&s_ch[t][1][3][lane][0];

            v16f accA = __builtin_amdgcn_mfma_f32_32x32x16_f16(ae,  b5,    Z,    0, 0, 0);
            v16f accB = __builtin_amdgcn_mfma_f32_32x32x16_f16(al0, bh[0], Z,    0, 0, 0);
            accA = __builtin_amdgcn_mfma_f32_32x32x16_f16(ah0, bh[0], accA, 0, 0, 0);
            accB = __builtin_amdgcn_mfma_f32_32x32x16_f16(al1, bh[1], accB, 0, 0, 0);
            accA = __builtin_amdgcn_mfma_f32_32x32x16_f16(ah1, bh[1], accA, 0, 0, 0);
            accB = __builtin_amdgcn_mfma_f32_32x32x16_f16(al2, bh[2], accB, 0, 0, 0);
            accA = __builtin_amdgcn_mfma_f32_32x32x16_f16(ah2, bh[2], accA, 0, 0, 0);
            accB = __builtin_amdgcn_mfma_f32_32x32x16_f16(al3, bh[3], accB, 0, 0, 0);
            accA = __builtin_amdgcn_mfma_f32_32x32x16_f16(ah3, bh[3], accA, 0, 0, 0);
            accB = __builtin_amdgcn_mfma_f32_32x32x16_f16(ah0, bl[0], accB, 0, 0, 0);
            accB = __builtin_amdgcn_mfma_f32_32x32x16_f16(ah1, bl[1], accB, 0, 0, 0);
            accB = __builtin_amdgcn_mfma_f32_32x32x16_f16(ah2, bl[2], accB, 0, 0, 0);
            accB = __builtin_amdgcn_mfma_f32_32x32x16_f16(ah3, bl[3], accB, 0, 0, 0);

            // exact value+slot top-2 tracking
            #pragma unroll
            for (int r = 0; r < 16; ++r) {
                const float s = accA[r] + accB[r];
                b2 = __builtin_amdgcn_fmed3f(s, bv, b2);
                if (s < bv) { bv = s; sl = (Tg << 4) | r; }
            }
        }
        __syncthreads();   // protect s_ch overwrite by next phase
    }

    // ---- cross-half-row merge (lane <-> lane^32), decode cw, flag near-ties ----
    {
        const float obv = __shfl_xor(bv, 32, 64);
        const float ob2 = __shfl_xor(b2, 32, 64);
        const int   osl = __shfl_xor(sl, 32, 64);
        const bool  oth = obv < bv;                 // strict: tie keeps lh=0's pick
        const float B1  = oth ? obv : bv;
        const float B2  = fminf(fmaxf(bv, obv), fminf(b2, ob2));
        const int   wsl = oth ? osl : sl;
        const int   wlh = oth ? (lh ^ 1) : lh;
        const int   r   = wsl & 15;
        const int   Tt  = wsl >> 4;                 // global tile 0..31
        const int   cw  = Tt * 32 + (r & 3) + 8 * (r >> 2) + 4 * wlh;
        if (lane < 32) {
            s_idx[q * 32 + lane] = cw;
            if (B2 - B1 < EPS) {
                const int pos = atomicAdd(&s_cnt, 1);
                s_list[pos] = q * 32 + lane;
            }
        }
    }
    __syncthreads();

    // ---- exact fp32 rescan, block-cooperative (rare: ~2e-4 of tokens) ----
    {
        const int cnt = s_cnt;
        const int rr  = tid >> 3;   // codeword row within 64-chunk, 0..63
        const int c   = tid & 7;    // d-octant (8 floats)
        for (int ii = 0; ii < cnt; ++ii) {
            const int tl = s_list[ii];
            if (tid < 64)
                s_xf[tid] = input[(size_t)b * DHW + (size_t)tid * HW + (hwb + tl)];
            __syncthreads();
            const float4* xs4 = (const float4*)&s_xf[c * 8];
            const float4 x0 = xs4[0], x1 = xs4[1];
            float bestv = INF; int bestk = K;
            #pragma unroll 4
            for (int i = 0; i < 16; ++i) {
                const int k = i * 64 + rr;               // ascending per thread
                const float4* c4 = (const float4*)(codebook + (size_t)k * D + c * 8);
                const float4 c0 = c4[0], c1 = c4[1];
                float p0 = 0.f, p1 = 0.f;
                p0 = fmaf(x0.x, c0.x, p0); p0 = fmaf(x0.y, c0.y, p0);
                p0 = fmaf(x0.z, c0.z, p0); p0 = fmaf(x0.w, c0.w, p0);
                p1 = fmaf(x1.x, c1.x, p1); p1 = fmaf(x1.y, c1.y, p1);
                p1 = fmaf(x1.z, c1.z, p1); p1 = fmaf(x1.w, c1.w, p1);
                float dp = p0 + p1;
                dp += __shfl_xor(dp, 1, 64);             // sum over 8 octants
                dp += __shfl_xor(dp, 2, 64);
                dp += __shfl_xor(dp, 4, 64);
                const float s = fmaf(-2.0f, dp, s_esq[k]);
                if (s < bestv) { bestv = s; bestk = k; }
            }
            #pragma unroll
            for (int off = 8; off <= 32; off <<= 1) {    // reduce rows within wave
                const float ov = __shfl_xor(bestv, off, 64);
                const int   ok = __shfl_xor(bestk, off, 64);
                if (ov < bestv || (ov == bestv && ok < bestk)) { bestv = ov; bestk = ok; }
            }
            if (lane == 0) { s_redv[q] = bestv; s_redk[q] = bestk; }
            __syncthreads();
            if (tid == 0) {
                float bb = s_redv[0]; int bk = s_redk[0];
                #pragma unroll
                for (int w = 1; w < 8; ++w) {
                    const float v = s_redv[w]; const int kk = s_redk[w];
                    if (v < bb || (v == bb && kk < bk)) { bb = v; bk = kk; }
                }
                s_idx[tl] = bk;
            }
            __syncthreads();
        }
    }

    // ---- epilogue: per-channel coalesced stores (thread = token x d-half) ----
    {
        const int token = tid & 255;
        const int dh    = tid >> 8;                      // 0/1
        const int idx   = s_idx[token];
        const float4* c4 = (const float4*)(codebook + (size_t)idx * D + dh * 32);
        float4 cr[8];
        #pragma unroll
        for (int j = 0; j < 8; ++j) cr[j] = c4[j];
        float* ob = out + (size_t)b * DHW + (size_t)dh * 32 * HW + hwb + token;
        #pragma unroll
        for (int j = 0; j < 8; ++j) {
            ob[(size_t)(4 * j + 0) * HW] = cr[j].x;
            ob[(size_t)(4 * j + 1) * HW] = cr[j].y;
            ob[(size_t)(4 * j + 2) * HW] = cr[j].z;
            ob[(size_t)(4 * j + 3) * HW] = cr[j].w;
        }
        if (tid < 256) out[OUT_ELEMS + tok0 + tid] = (float)s_idx[tid];
    }
}

extern "C" void kernel_launch(void* const* d_in, const int* in_sizes, int n_in,
                              void* d_out, int out_size, void* d_ws, size_t ws_size,
                              hipStream_t stream) {
    const float* input    = (const float*)d_in[0];
    const float* codebook = (const float*)d_in[1];
    float* out            = (float*)d_out;
    vq_fused<<<256, 512, 0, stream>>>(input, codebook, out);
}